// Round 3
// baseline (1024.938 us; speedup 1.0000x reference)
//
#include <hip/hip_runtime.h>

#define N_ROWS   131072
#define D_IN     512
#define D_H      128
#define K_CODES  256
#define NT       256          // 4 waves
#define RPB      64           // rows per block: 16 per wave (one MFMA row-tile)
#define NBLK     (N_ROWS / RPB)
#define SA       136          // LDS row stride in bf16 elems (272 B)
#define SB       136

typedef __attribute__((ext_vector_type(8))) short bf16x8;
typedef __attribute__((ext_vector_type(4))) float f32x4;

__device__ inline unsigned short f2bf(float f) {
    unsigned u = __float_as_uint(f);
    return (unsigned short)((u + 0x7FFFu + ((u >> 16) & 1u)) >> 16);
}
__device__ inline ushort4 f2bf4(float4 v) {
    return make_ushort4(f2bf(v.x), f2bf(v.y), f2bf(v.z), f2bf(v.w));
}

__global__ __launch_bounds__(NT, 3) void rqvae_main(
    const float* __restrict__ emb,
    const float* __restrict__ Wenc,   // [128][512]
    const float* __restrict__ Wdec,   // [512][128]
    const float* __restrict__ cb0,    // [256][128]
    const float* __restrict__ cb1,
    const float* __restrict__ cb2,
    float* __restrict__ acc_rq,
    float* __restrict__ acc_recon,
    int* __restrict__ used)           // [3][256]
{
    __shared__ unsigned short s_A[RPB * SA];   // 17408 B : A operand (emb chunk / rem / restored)
    __shared__ unsigned short s_B[128 * SB];   // 34816 B : B operand (Wenc / cb half / Wdec chunk)
    __shared__ float s_cn[K_CODES];            // 1024 B  : -0.5*||c||^2 for current stage

    const int tid  = threadIdx.x;
    const int wv   = tid >> 6;
    const int lane = tid & 63;
    const int nn   = lane & 15;      // MFMA m/n index
    const int qd   = lane >> 4;      // quad id 0..3
    const long blkRow = (long)blockIdx.x * RPB;
    const float* cbs[3] = {cb0, cb1, cb2};

    // rem/res in MFMA C-layout: element (row = wv*16 + qd*4 + e, col = ct*16 + nn)
    f32x4 rem[8], res[8];
    #pragma unroll
    for (int ct = 0; ct < 8; ++ct) { rem[ct] = {0.f,0.f,0.f,0.f}; res[ct] = {0.f,0.f,0.f,0.f}; }

    // ---- Phase 1: latent = emb @ Wenc^T (K=512, 4 chunks of 128) ----
    for (int kc = 0; kc < 4; ++kc) {
        __syncthreads();
        #pragma unroll
        for (int it = 0; it < 8; ++it) {        // A: 64 rows x 32 float4
            const int g = tid + it * NT, row = g >> 5, c4 = g & 31;
            float4 v = *(const float4*)(emb + (blkRow + row) * D_IN + kc * 128 + c4 * 4);
            *(ushort4*)&s_A[row * SA + c4 * 4] = f2bf4(v);
        }
        #pragma unroll
        for (int it = 0; it < 16; ++it) {       // B: 128 rows x 32 float4
            const int g = tid + it * NT, row = g >> 5, c4 = g & 31;
            float4 w = *(const float4*)(Wenc + (long)row * D_IN + kc * 128 + c4 * 4);
            *(ushort4*)&s_B[row * SB + c4 * 4] = f2bf4(w);
        }
        __syncthreads();
        const int arow = wv * 16 + nn;
        bf16x8 af[4];
        #pragma unroll
        for (int ks = 0; ks < 4; ++ks) af[ks] = *(const bf16x8*)&s_A[arow * SA + ks * 32 + qd * 8];
        #pragma unroll
        for (int ct = 0; ct < 8; ++ct)
            #pragma unroll
            for (int ks = 0; ks < 4; ++ks) {
                bf16x8 bf = *(const bf16x8*)&s_B[(ct * 16 + nn) * SB + ks * 32 + qd * 8];
                rem[ct] = __builtin_amdgcn_mfma_f32_16x16x32_bf16(af[ks], bf, rem[ct], 0, 0, 0);
            }
    }

    // rem (=latent) -> s_A bf16 (wave-private rows, no barrier needed)
    #pragma unroll
    for (int ct = 0; ct < 8; ++ct)
        #pragma unroll
        for (int e = 0; e < 4; ++e)
            s_A[(wv * 16 + qd * 4 + e) * SA + ct * 16 + nn] = f2bf(rem[ct][e]);

    // ---- Phase 2: three RQ stages ----
    float local_rq = 0.f;
    for (int t = 0; t < 3; ++t) {
        const float* __restrict__ cb = cbs[t];
        __syncthreads();                      // protect s_B/s_cn from previous readers
        {   // -0.5*||c_tid||^2 in fp32
            const float4* r = (const float4*)(cb + (long)tid * D_H);
            float s = 0.f;
            #pragma unroll
            for (int d = 0; d < 32; ++d) { float4 v = r[d]; s += v.x*v.x + v.y*v.y + v.z*v.z + v.w*v.w; }
            s_cn[tid] = -0.5f * s;
        }
        float bv[4]; int bi[4];
        #pragma unroll
        for (int e = 0; e < 4; ++e) { bv[e] = -3.402823466e38f; bi[e] = 0; }

        for (int half = 0; half < 2; ++half) {
            if (half) __syncthreads();
            #pragma unroll
            for (int it = 0; it < 16; ++it) {
                const int g = tid + it * NT, row = g >> 5, c4 = g & 31;
                float4 v = *(const float4*)(cb + (long)(half * 128 + row) * D_H + c4 * 4);
                *(ushort4*)&s_B[row * SB + c4 * 4] = f2bf4(v);
            }
            __syncthreads();
            const int arow = wv * 16 + nn;
            bf16x8 af[4];
            #pragma unroll
            for (int ks = 0; ks < 4; ++ks) af[ks] = *(const bf16x8*)&s_A[arow * SA + ks * 32 + qd * 8];
            f32x4 sc[8];
            #pragma unroll
            for (int ct = 0; ct < 8; ++ct) sc[ct] = {0.f,0.f,0.f,0.f};
            #pragma unroll
            for (int ct = 0; ct < 8; ++ct)
                #pragma unroll
                for (int ks = 0; ks < 4; ++ks) {
                    bf16x8 bf = *(const bf16x8*)&s_B[(ct * 16 + nn) * SB + ks * 32 + qd * 8];
                    sc[ct] = __builtin_amdgcn_mfma_f32_16x16x32_bf16(af[ks], bf, sc[ct], 0, 0, 0);
                }
            #pragma unroll
            for (int ct = 0; ct < 8; ++ct) {
                const int code = half * 128 + ct * 16 + nn;
                const float cn = s_cn[code];
                #pragma unroll
                for (int e = 0; e < 4; ++e) {
                    const float val = sc[ct][e] + cn;
                    if (val > bv[e] || (val == bv[e] && code < bi[e])) { bv[e] = val; bi[e] = code; }
                }
            }
        }
        // argmax across the 16 lanes of each quad (tie -> lowest index)
        #pragma unroll
        for (int e = 0; e < 4; ++e) {
            float v = bv[e]; int i0 = bi[e];
            #pragma unroll
            for (int m = 8; m >= 1; m >>= 1) {
                const float ov = __shfl_xor(v, m);
                const int   oi = __shfl_xor(i0, m);
                if (ov > v || (ov == v && oi < i0)) { v = ov; i0 = oi; }
            }
            bi[e] = i0;
            if (nn == 0) used[t * K_CODES + i0] = 1;
        }
        // update rem/res with fp32 codebook rows
        #pragma unroll
        for (int ct = 0; ct < 8; ++ct)
            #pragma unroll
            for (int e = 0; e < 4; ++e) {
                const float c = cb[(long)bi[e] * D_H + ct * 16 + nn];
                const float r = rem[ct][e] - c;
                rem[ct][e] = r;
                res[ct][e] += c;
                local_rq += r * r;
                if (t < 2)
                    s_A[(wv * 16 + qd * 4 + e) * SA + ct * 16 + nn] = f2bf(r);
            }
    }

    // restored -> s_A bf16 (wave-private)
    #pragma unroll
    for (int ct = 0; ct < 8; ++ct)
        #pragma unroll
        for (int e = 0; e < 4; ++e)
            s_A[(wv * 16 + qd * 4 + e) * SA + ct * 16 + nn] = f2bf(res[ct][e]);

    // ---- Phase 3: recon = restored @ Wdec^T, diff vs fp32 emb ----
    float local_rec = 0.f;
    for (int c = 0; c < 4; ++c) {
        __syncthreads();
        #pragma unroll
        for (int it = 0; it < 16; ++it) {
            const int g = tid + it * NT, row = g >> 5, c4 = g & 31;
            float4 v = *(const float4*)(Wdec + (long)(c * 128 + row) * D_H + c4 * 4);
            *(ushort4*)&s_B[row * SB + c4 * 4] = f2bf4(v);
        }
        __syncthreads();
        const int arow = wv * 16 + nn;
        bf16x8 af[4];
        #pragma unroll
        for (int ks = 0; ks < 4; ++ks) af[ks] = *(const bf16x8*)&s_A[arow * SA + ks * 32 + qd * 8];
        f32x4 rc[8];
        #pragma unroll
        for (int ct = 0; ct < 8; ++ct) rc[ct] = {0.f,0.f,0.f,0.f};
        #pragma unroll
        for (int ct = 0; ct < 8; ++ct)
            #pragma unroll
            for (int ks = 0; ks < 4; ++ks) {
                bf16x8 bf = *(const bf16x8*)&s_B[(ct * 16 + nn) * SB + ks * 32 + qd * 8];
                rc[ct] = __builtin_amdgcn_mfma_f32_16x16x32_bf16(af[ks], bf, rc[ct], 0, 0, 0);
            }
        #pragma unroll
        for (int ct = 0; ct < 8; ++ct)
            #pragma unroll
            for (int e = 0; e < 4; ++e) {
                const long row = blkRow + wv * 16 + qd * 4 + e;
                const float ev = emb[row * D_IN + c * 128 + ct * 16 + nn];
                const float d = rc[ct][e] - ev;
                local_rec += d * d;
            }
    }

    // ---- wave shuffle reduce, one atomic pair per wave ----
    float r1 = local_rq, r2 = local_rec;
    #pragma unroll
    for (int m = 32; m >= 1; m >>= 1) { r1 += __shfl_xor(r1, m); r2 += __shfl_xor(r2, m); }
    if (lane == 0) { atomicAdd(acc_rq, r1); atomicAdd(acc_recon, r2); }
}

__global__ void rqvae_finalize(const float* __restrict__ acc,
                               const int* __restrict__ used,
                               float* __restrict__ out)
{
    __shared__ int s_sum[4];
    const int tid = threadIdx.x;
    for (int t = 0; t < 3; ++t) {
        int v = (used[t * K_CODES + tid] != 0) ? 1 : 0;
        #pragma unroll
        for (int off = 32; off >= 1; off >>= 1) v += __shfl_down(v, off);
        if ((tid & 63) == 0) s_sum[tid >> 6] = v;
        __syncthreads();
        if (tid == 0) out[3 + t] = (float)(s_sum[0] + s_sum[1] + s_sum[2] + s_sum[3]);
        __syncthreads();
    }
    if (tid == 0) {
        const float rq    = 1.25f * acc[0] / ((float)N_ROWS * 128.0f);
        const float recon =         acc[1] / ((float)N_ROWS * 512.0f);
        out[0] = recon + rq;
        out[1] = recon;
        out[2] = rq;
    }
}

extern "C" void kernel_launch(void* const* d_in, const int* in_sizes, int n_in,
                              void* d_out, int out_size, void* d_ws, size_t ws_size,
                              hipStream_t stream) {
    const float* emb  = (const float*)d_in[0];
    const float* Wenc = (const float*)d_in[1];
    const float* Wdec = (const float*)d_in[2];
    const float* cb0  = (const float*)d_in[3];
    const float* cb1  = (const float*)d_in[4];
    const float* cb2  = (const float*)d_in[5];

    float* ws_f = (float*)d_ws;          // [0]=rq_sum, [1]=recon_sum
    int*   used = (int*)d_ws + 16;       // 3*256 flags

    hipMemsetAsync(d_ws, 0, (16 + 3 * K_CODES) * sizeof(int), stream);
    rqvae_main<<<NBLK, NT, 0, stream>>>(
        emb, Wenc, Wdec, cb0, cb1, cb2, ws_f + 0, ws_f + 1, used);
    rqvae_finalize<<<1, K_CODES, 0, stream>>>(ws_f, used, (float*)d_out);
}

// Round 4
// 551.691 us; speedup vs baseline: 1.8578x; 1.8578x over previous
//
#include <hip/hip_runtime.h>

#define N_ROWS   131072
#define D_IN     512
#define D_H      128
#define K_CODES  256
#define NT       256          // 4 waves
#define RPB      128          // rows per block: 32 per wave (2 x 16-row MFMA tiles)
#define NBLK     (N_ROWS / RPB)
#define SA       136          // s_A row stride in bf16 elems (272 B, breaks power-of-2)

typedef __attribute__((ext_vector_type(8))) short bf16x8;
typedef __attribute__((ext_vector_type(4))) float f32x4;

__device__ inline unsigned short f2bf(float f) {
    unsigned u = __float_as_uint(f);
    return (unsigned short)((u + 0x7FFFu + ((u >> 16) & 1u)) >> 16);
}
__device__ inline ushort4 f2bf4(float4 v) {
    return make_ushort4(f2bf(v.x), f2bf(v.y), f2bf(v.z), f2bf(v.w));
}

// ---------------- prep: reorder weights/codebooks into MFMA B-fragment order ----------------
// B-fragment order: frag(ct,ks) is 64 lanes x 8 bf16, lane = qd*16+nn holds
// B[n = ct*16+nn][k = ks*32 + qd*8 + j], j=0..7.  One 32KB "round" = 8 ct x 4 ks.
// wsb layout (ushorts): [0..65535] Wenc rounds kc=0..3 | [65536..163839] cb (t,half) rounds | [163840..229375] Wdec rounds c=0..3
__global__ void rqvae_prep(const float* __restrict__ Wenc,
                           const float* __restrict__ Wdec,
                           const float* __restrict__ cb0,
                           const float* __restrict__ cb1,
                           const float* __restrict__ cb2,
                           unsigned short* __restrict__ wsb,
                           float* __restrict__ norms)
{
    const int tid = threadIdx.x;
    const int b = blockIdx.x;
    const float* cbs[3] = {cb0, cb1, cb2};
    if (b < 112) {
        const int g = b * 256 + tid;            // ushort8 group id, 0..28671
        const int lane = g & 63, ks = (g >> 6) & 3, ct = (g >> 8) & 7;
        const int nn = lane & 15, qd = lane >> 4;
        const float* src;
        if (g < 8192) {                         // Wenc: kc = g>>11
            const int kc = g >> 11;
            src = Wenc + (ct * 16 + nn) * D_IN + kc * 128 + ks * 32 + qd * 8;
        } else if (g < 20480) {                 // cb: t = (g-8192)>>12, half = bit 11
            const int r = g - 8192;
            const int t = r >> 12, half = (r >> 11) & 1;
            src = cbs[t] + (long)(half * 128 + ct * 16 + nn) * D_H + ks * 32 + qd * 8;
        } else {                                // Wdec: c = (g-20480)>>11
            const int r = g - 20480;
            const int c = r >> 11;
            src = Wdec + (long)(c * 128 + ct * 16 + nn) * D_H + ks * 32 + qd * 8;
        }
        float4 v0 = *(const float4*)(src);
        float4 v1 = *(const float4*)(src + 4);
        *(ushort4*)(wsb + (long)g * 8)     = f2bf4(v0);
        *(ushort4*)(wsb + (long)g * 8 + 4) = f2bf4(v1);
    } else {
        const int t = b - 112;                  // norm blocks: one code per thread
        const float4* r = (const float4*)(cbs[t] + (long)tid * D_H);
        float s = 0.f;
        #pragma unroll
        for (int d = 0; d < 32; ++d) { float4 v = r[d]; s += v.x*v.x + v.y*v.y + v.z*v.z + v.w*v.w; }
        norms[t * K_CODES + tid] = -0.5f * s;
    }
}

// ---------------- main ----------------
__global__ __launch_bounds__(NT, 2) void rqvae_main(
    const float* __restrict__ emb,
    const float* __restrict__ cb0,
    const float* __restrict__ cb1,
    const float* __restrict__ cb2,
    const unsigned short* __restrict__ wsb,
    const float* __restrict__ norms,
    float* __restrict__ acc_rq,
    float* __restrict__ acc_recon,
    int* __restrict__ used)
{
    __shared__ unsigned short s_A[RPB * SA];   // 34816 B: A operand (emb chunk / rem / restored), padded
    __shared__ unsigned short s_B[16384];      // 32768 B: one B round, fragment-linear
    __shared__ float s_cn[3 * K_CODES];        // 3072 B

    const int tid  = threadIdx.x;
    const int wv   = tid >> 6;
    const int lane = tid & 63;
    const int nn   = lane & 15;
    const int qd   = lane >> 4;
    const long blkRow = (long)blockIdx.x * RPB;
    const float* cbs[3] = {cb0, cb1, cb2};

    for (int i = tid; i < 3 * K_CODES; i += NT) s_cn[i] = norms[i];

    f32x4 rem[2][8], res[2][8];
    #pragma unroll
    for (int rt = 0; rt < 2; ++rt)
        #pragma unroll
        for (int ct = 0; ct < 8; ++ct) { rem[rt][ct] = {0.f,0.f,0.f,0.f}; res[rt][ct] = {0.f,0.f,0.f,0.f}; }

    // ---- Phase 1: latent = emb @ Wenc^T (4 rounds of K=128) ----
    for (int kc = 0; kc < 4; ++kc) {
        __syncthreads();
        #pragma unroll
        for (int it = 0; it < 16; ++it) {                   // A: 128 rows x 32 float4
            const int g = tid + it * NT, row = g >> 5, c4 = g & 31;
            float4 v = *(const float4*)(emb + (blkRow + row) * D_IN + kc * 128 + c4 * 4);
            *(ushort4*)&s_A[row * SA + c4 * 4] = f2bf4(v);
        }
        {   // B: straight 32KB copy, fragment-linear
            const bf16x8* src = (const bf16x8*)(wsb + kc * 16384);
            bf16x8* dst = (bf16x8*)s_B;
            #pragma unroll
            for (int i = 0; i < 8; ++i) dst[tid + i * NT] = src[tid + i * NT];
        }
        __syncthreads();
        bf16x8 af[2][4];
        #pragma unroll
        for (int rt = 0; rt < 2; ++rt)
            #pragma unroll
            for (int ks = 0; ks < 4; ++ks)
                af[rt][ks] = *(const bf16x8*)&s_A[(wv * 32 + rt * 16 + nn) * SA + ks * 32 + qd * 8];
        #pragma unroll
        for (int ct = 0; ct < 8; ++ct)
            #pragma unroll
            for (int ks = 0; ks < 4; ++ks) {
                bf16x8 bf = *(const bf16x8*)&s_B[(ct * 4 + ks) * 512 + lane * 8];
                rem[0][ct] = __builtin_amdgcn_mfma_f32_16x16x32_bf16(af[0][ks], bf, rem[0][ct], 0, 0, 0);
                rem[1][ct] = __builtin_amdgcn_mfma_f32_16x16x32_bf16(af[1][ks], bf, rem[1][ct], 0, 0, 0);
            }
    }

    // latent -> s_A bf16 (wave-private rows)
    #pragma unroll
    for (int rt = 0; rt < 2; ++rt)
        #pragma unroll
        for (int ct = 0; ct < 8; ++ct)
            #pragma unroll
            for (int e = 0; e < 4; ++e)
                s_A[(wv * 32 + rt * 16 + qd * 4 + e) * SA + ct * 16 + nn] = f2bf(rem[rt][ct][e]);

    // ---- Phase 2: three RQ stages ----
    float local_rq = 0.f;
    for (int t = 0; t < 3; ++t) {
        const float* __restrict__ cb = cbs[t];
        float bv[2][4]; int bi[2][4];
        #pragma unroll
        for (int rt = 0; rt < 2; ++rt)
            #pragma unroll
            for (int e = 0; e < 4; ++e) { bv[rt][e] = -3.402823466e38f; bi[rt][e] = 0; }

        bf16x8 af[2][4];
        #pragma unroll
        for (int rt = 0; rt < 2; ++rt)
            #pragma unroll
            for (int ks = 0; ks < 4; ++ks)
                af[rt][ks] = *(const bf16x8*)&s_A[(wv * 32 + rt * 16 + nn) * SA + ks * 32 + qd * 8];

        for (int half = 0; half < 2; ++half) {
            __syncthreads();
            {
                const bf16x8* src = (const bf16x8*)(wsb + 65536 + (t * 2 + half) * 16384);
                bf16x8* dst = (bf16x8*)s_B;
                #pragma unroll
                for (int i = 0; i < 8; ++i) dst[tid + i * NT] = src[tid + i * NT];
            }
            __syncthreads();
            #pragma unroll
            for (int ct = 0; ct < 8; ++ct) {
                f32x4 s0 = {0.f,0.f,0.f,0.f}, s1 = {0.f,0.f,0.f,0.f};
                #pragma unroll
                for (int ks = 0; ks < 4; ++ks) {
                    bf16x8 bf = *(const bf16x8*)&s_B[(ct * 4 + ks) * 512 + lane * 8];
                    s0 = __builtin_amdgcn_mfma_f32_16x16x32_bf16(af[0][ks], bf, s0, 0, 0, 0);
                    s1 = __builtin_amdgcn_mfma_f32_16x16x32_bf16(af[1][ks], bf, s1, 0, 0, 0);
                }
                const int code = half * 128 + ct * 16 + nn;
                const float cn = s_cn[t * K_CODES + code];
                #pragma unroll
                for (int e = 0; e < 4; ++e) {
                    const float v0 = s0[e] + cn;
                    if (v0 > bv[0][e] || (v0 == bv[0][e] && code < bi[0][e])) { bv[0][e] = v0; bi[0][e] = code; }
                    const float v1 = s1[e] + cn;
                    if (v1 > bv[1][e] || (v1 == bv[1][e] && code < bi[1][e])) { bv[1][e] = v1; bi[1][e] = code; }
                }
            }
        }
        // argmax over the 16 nn-lanes of each quad (tie -> lowest index)
        #pragma unroll
        for (int rt = 0; rt < 2; ++rt)
            #pragma unroll
            for (int e = 0; e < 4; ++e) {
                float v = bv[rt][e]; int i0 = bi[rt][e];
                #pragma unroll
                for (int m = 8; m >= 1; m >>= 1) {
                    const float ov = __shfl_xor(v, m);
                    const int   oi = __shfl_xor(i0, m);
                    if (ov > v || (ov == v && oi < i0)) { v = ov; i0 = oi; }
                }
                bi[rt][e] = i0;
                if (nn == 0) used[t * K_CODES + i0] = 1;
            }
        // update rem/res with fp32 codebook rows
        #pragma unroll
        for (int rt = 0; rt < 2; ++rt)
            #pragma unroll
            for (int ct = 0; ct < 8; ++ct)
                #pragma unroll
                for (int e = 0; e < 4; ++e) {
                    const float c = cb[(long)bi[rt][e] * D_H + ct * 16 + nn];
                    const float r = rem[rt][ct][e] - c;
                    rem[rt][ct][e] = r;
                    res[rt][ct][e] += c;
                    local_rq += r * r;
                    if (t < 2)
                        s_A[(wv * 32 + rt * 16 + qd * 4 + e) * SA + ct * 16 + nn] = f2bf(r);
                }
    }

    // restored -> s_A bf16 (wave-private)
    #pragma unroll
    for (int rt = 0; rt < 2; ++rt)
        #pragma unroll
        for (int ct = 0; ct < 8; ++ct)
            #pragma unroll
            for (int e = 0; e < 4; ++e)
                s_A[(wv * 32 + rt * 16 + qd * 4 + e) * SA + ct * 16 + nn] = f2bf(res[rt][ct][e]);

    // ---- Phase 3: recon = restored @ Wdec^T, diff vs fp32 emb ----
    float local_rec = 0.f;
    {
        bf16x8 af[2][4];
        #pragma unroll
        for (int rt = 0; rt < 2; ++rt)
            #pragma unroll
            for (int ks = 0; ks < 4; ++ks)
                af[rt][ks] = *(const bf16x8*)&s_A[(wv * 32 + rt * 16 + nn) * SA + ks * 32 + qd * 8];
        for (int c = 0; c < 4; ++c) {
            __syncthreads();
            {
                const bf16x8* src = (const bf16x8*)(wsb + 163840 + c * 16384);
                bf16x8* dst = (bf16x8*)s_B;
                #pragma unroll
                for (int i = 0; i < 8; ++i) dst[tid + i * NT] = src[tid + i * NT];
            }
            __syncthreads();
            #pragma unroll
            for (int ct = 0; ct < 8; ++ct) {
                f32x4 r0 = {0.f,0.f,0.f,0.f}, r1 = {0.f,0.f,0.f,0.f};
                #pragma unroll
                for (int ks = 0; ks < 4; ++ks) {
                    bf16x8 bf = *(const bf16x8*)&s_B[(ct * 4 + ks) * 512 + lane * 8];
                    r0 = __builtin_amdgcn_mfma_f32_16x16x32_bf16(af[0][ks], bf, r0, 0, 0, 0);
                    r1 = __builtin_amdgcn_mfma_f32_16x16x32_bf16(af[1][ks], bf, r1, 0, 0, 0);
                }
                const int col = c * 128 + ct * 16 + nn;
                #pragma unroll
                for (int e = 0; e < 4; ++e) {
                    const float e0 = emb[(blkRow + wv * 32 +      qd * 4 + e) * D_IN + col];
                    const float e1 = emb[(blkRow + wv * 32 + 16 + qd * 4 + e) * D_IN + col];
                    const float d0 = r0[e] - e0;
                    const float d1 = r1[e] - e1;
                    local_rec += d0 * d0 + d1 * d1;
                }
            }
        }
    }

    // ---- wave shuffle reduce, one atomic pair per wave ----
    float r1 = local_rq, r2 = local_rec;
    #pragma unroll
    for (int m = 32; m >= 1; m >>= 1) { r1 += __shfl_xor(r1, m); r2 += __shfl_xor(r2, m); }
    if (lane == 0) { atomicAdd(acc_rq, r1); atomicAdd(acc_recon, r2); }
}

__global__ void rqvae_finalize(const float* __restrict__ acc,
                               const int* __restrict__ used,
                               float* __restrict__ out)
{
    __shared__ int s_sum[4];
    const int tid = threadIdx.x;
    for (int t = 0; t < 3; ++t) {
        int v = (used[t * K_CODES + tid] != 0) ? 1 : 0;
        #pragma unroll
        for (int off = 32; off >= 1; off >>= 1) v += __shfl_down(v, off);
        if ((tid & 63) == 0) s_sum[tid >> 6] = v;
        __syncthreads();
        if (tid == 0) out[3 + t] = (float)(s_sum[0] + s_sum[1] + s_sum[2] + s_sum[3]);
        __syncthreads();
    }
    if (tid == 0) {
        const float rq    = 1.25f * acc[0] / ((float)N_ROWS * 128.0f);
        const float recon =         acc[1] / ((float)N_ROWS * 512.0f);
        out[0] = recon + rq;
        out[1] = recon;
        out[2] = rq;
    }
}

extern "C" void kernel_launch(void* const* d_in, const int* in_sizes, int n_in,
                              void* d_out, int out_size, void* d_ws, size_t ws_size,
                              hipStream_t stream) {
    const float* emb  = (const float*)d_in[0];
    const float* Wenc = (const float*)d_in[1];
    const float* Wdec = (const float*)d_in[2];
    const float* cb0  = (const float*)d_in[3];
    const float* cb1  = (const float*)d_in[4];
    const float* cb2  = (const float*)d_in[5];

    // workspace layout (bytes): [0] 2 f32 acc | [64] 768 int used | [3200] 768 f32 norms | [8192] 448KB bf16 frags
    float* ws_f  = (float*)d_ws;
    int*   used  = (int*)((char*)d_ws + 64);
    float* norms = (float*)((char*)d_ws + 3200);
    unsigned short* wsb = (unsigned short*)((char*)d_ws + 8192);

    hipMemsetAsync(d_ws, 0, 3200, stream);
    rqvae_prep<<<115, NT, 0, stream>>>(Wenc, Wdec, cb0, cb1, cb2, wsb, norms);
    rqvae_main<<<NBLK, NT, 0, stream>>>(emb, cb0, cb1, cb2, wsb, norms,
                                        ws_f + 0, ws_f + 1, used);
    rqvae_finalize<<<1, K_CODES, 0, stream>>>(ws_f, used, (float*)d_out);
}